// Round 9
// baseline (1139.803 us; speedup 1.0000x reference)
//
#include <hip/hip_runtime.h>
#include <hip/hip_bf16.h>
#include <math.h>

#define NTOK   8192      // B*S tokens
#define NEXP   64
#define EMBD   1024
#define MLPD   2048
#define TOPK   2
#define NFLAT  (NTOK * TOPK)
#define BKD    32        // K tile
#define MAXCH  8         // max m-chunks of 128 (mean Me=256)

typedef __attribute__((ext_vector_type(4)))  float  f32x4;
typedef __attribute__((ext_vector_type(16))) float  f32x16;
typedef __attribute__((ext_vector_type(8)))  __bf16 bf16x8;

// global -> LDS direct (16B/lane). LDS dest = wave-uniform base + lane*16.
__device__ __forceinline__ void gl16(const void* g, void* lds_base) {
  __builtin_amdgcn_global_load_lds(
      (const __attribute__((address_space(1))) unsigned int*)g,
      (__attribute__((address_space(3))) unsigned int*)lds_base, 16, 0, 0);
}

// ---------------- workspace layout (bytes) ----------------
#define OFF_COUNTS 0
#define OFF_BASE   256
#define OFF_RUN    512
#define OFF_EFLAT  1024
#define OFF_WFLAT  (1024 + 65536)
#define OFF_ROWTOK (1024 + 2 * 65536)
#define OFF_F2R    (1024 + 3 * 65536)
#define OFF_INTER  (1024 + 4 * 65536)                       // bf16 [16384][2048]
#define OFF_OS     (OFF_INTER + (size_t)NFLAT * MLPD * 2)   // out_sorted
#define NEED_F32   (OFF_OS + (size_t)NFLAT * EMBD * 4)

// ---------------- router: logits + top-2 + softmax ----------------
__global__ __launch_bounds__(256) void router_topk(
    const float* __restrict__ x, const float* __restrict__ gk,
    int* __restrict__ e_flat, float* __restrict__ w_flat) {
  int t = blockIdx.x * 4 + (threadIdx.x >> 6);
  int l = threadIdx.x & 63;
  const float* xr = x + (size_t)t * EMBD;
  float acc = 0.f;
  #pragma unroll 8
  for (int i = 0; i < EMBD; ++i)
    acc = fmaf(xr[i], gk[i * NEXP + l], acc);
  float m = acc;
  for (int o = 32; o; o >>= 1) m = fmaxf(m, __shfl_xor(m, o));
  unsigned long long b1 = __ballot(acc == m);
  int i1 = __ffsll(b1) - 1;
  float v2 = (l == i1) ? -INFINITY : acc;
  float m2 = v2;
  for (int o = 32; o; o >>= 1) m2 = fmaxf(m2, __shfl_xor(m2, o));
  unsigned long long b2 = __ballot(v2 == m2);
  int i2 = __ffsll(b2) - 1;
  if (l == 0) {
    float e2 = expf(m2 - m);
    float inv = 1.f / (1.f + e2);
    e_flat[2 * t] = i1;  e_flat[2 * t + 1] = i2;
    w_flat[2 * t] = inv; w_flat[2 * t + 1] = e2 * inv;
  }
}

// ---------------- histogram / scan / scatter ----------------
__global__ void hist_k(const int* __restrict__ ef, int* __restrict__ counts) {
  int j = blockIdx.x * 256 + threadIdx.x;
  if (j < NFLAT) atomicAdd(&counts[ef[j]], 1);
}

__global__ void scan_k(const int* __restrict__ counts, int* __restrict__ base) {
  if (threadIdx.x == 0) {
    int s = 0;
    for (int e = 0; e < NEXP; ++e) { base[e] = s; s += counts[e]; }
  }
}

__global__ void scatter_k(const int* __restrict__ ef, const int* __restrict__ base,
                          int* __restrict__ run, int* __restrict__ rowtok,
                          int* __restrict__ f2r) {
  int j = blockIdx.x * 256 + threadIdx.x;
  if (j < NFLAT) {
    int e = ef[j];
    int r = base[e] + atomicAdd(&run[e], 1);
    f2r[j] = r;
    rowtok[r] = j >> 1;
  }
}

// ---------------- grouped GEMM 1: inter = silu(x@w0) * (x@w1) ----------------
// 128m x 64n x 32k; 4 waves 2x2 (wave 64m x 32n); MFMA 32x32x16.
// A: gl_lds fragment-major, DOUBLE-buffered, cooperative (wave wv stages its
//    m-group g=wv; 4 gl16/wave/step). B: REGISTER-DIRECT from global (no LDS),
//    depth-2: B(ks+2) issued at phase ks; cvt to bf16 at phase start.
// One barrier/phase; counted vmcnt(32) leaves B(ks+1) in flight.
__global__ __launch_bounds__(256, 2) void gemm1_k(
    const float* __restrict__ x, const float* __restrict__ w0,
    const float* __restrict__ w1, const int* __restrict__ counts,
    const int* __restrict__ base, const int* __restrict__ rowtok,
    __hip_bfloat16* __restrict__ inter) {
  int e = blockIdx.z;
  int Me = counts[e];
  int mc = blockIdx.y;
  if (mc * 128 >= Me) return;
  int rs = base[e];
  int nb = blockIdx.x * 64;
  int t = threadIdx.x;
  int wv = t >> 6, l = t & 63;
  int wr = wv >> 1, wc = wv & 1;
  int lo = l & 31, hi = l >> 5;
  int hi8 = hi * 8;

  __shared__ float Ash[2][4096];   // 2 x 16KB [slot16][lane64][4f]

  // A staging: wave wv stages m-group g=wv (rows mc*128+wv*32+lo)
  int rga = mc * 128 + wv * 32 + lo; rga = rga < Me ? rga : Me - 1;
  const float* abase = x + (size_t)rowtok[rs + rga] * EMBD + hi * 4;
  // B register-direct: column n = nb + wc*32 + lo, k strided by MLPD
  const float* bsrc0 = w0 + (size_t)e * EMBD * MLPD + nb + wc * 32 + lo;
  const float* bsrc1 = w1 + (size_t)e * EMBD * MLPD + nb + wc * 32 + lo;

  float br[2][2][2][8];   // [set][mat][kh][q] - all indices compile-time
  f32x16 acc0[2], acc1[2];
  #pragma unroll
  for (int g = 0; g < 2; ++g)
    #pragma unroll
    for (int r = 0; r < 16; ++r) { acc0[g][r] = 0.f; acc1[g][r] = 0.f; }

  const int NT = EMBD / BKD;  // 32 (even)

  // prologue: A(0) -> buf0; B(0) -> set0; B(1) -> set1
  #pragma unroll
  for (int h = 0; h < 4; ++h)
    gl16(abase + h * 8, &Ash[0][(wv * 4 + h) * 256]);
  #pragma unroll
  for (int m = 0; m < 2; ++m)
    #pragma unroll
    for (int kh = 0; kh < 2; ++kh)
      #pragma unroll
      for (int q = 0; q < 8; ++q) {
        br[0][m][kh][q] = (m ? bsrc1 : bsrc0)[(size_t)(kh * 16 + hi8 + q) * MLPD];
        br[1][m][kh][q] = (m ? bsrc1 : bsrc0)[(size_t)(BKD + kh * 16 + hi8 + q) * MLPD];
      }

#define G1_PHASE(cur, ks)                                                           \
  {                                                                                 \
    if ((ks) + 1 < NT) asm volatile("s_waitcnt vmcnt(32)" ::: "memory");            \
    else               asm volatile("s_waitcnt vmcnt(0)" ::: "memory");             \
    __builtin_amdgcn_s_barrier();                                                   \
    bf16x8 bv0[2], bv1[2];                                                          \
    _Pragma("unroll")                                                               \
    for (int kh = 0; kh < 2; ++kh)                                                  \
      _Pragma("unroll")                                                             \
      for (int q = 0; q < 8; ++q) {                                                 \
        bv0[kh][q] = (__bf16)br[cur][0][kh][q];                                     \
        bv1[kh][q] = (__bf16)br[cur][1][kh][q];                                     \
      }                                                                             \
    __builtin_amdgcn_sched_barrier(0);                                              \
    if ((ks) + 1 < NT) {                                                            \
      _Pragma("unroll")                                                             \
      for (int h = 0; h < 4; ++h)                                                   \
        gl16(abase + ((ks) + 1) * BKD + h * 8, &Ash[(cur) ^ 1][(wv * 4 + h) * 256]);\
    }                                                                               \
    __builtin_amdgcn_sched_barrier(0);                                              \
    if ((ks) + 2 < NT) {                                                            \
      _Pragma("unroll")                                                             \
      for (int m = 0; m < 2; ++m)                                                   \
        _Pragma("unroll")                                                           \
        for (int kh = 0; kh < 2; ++kh)                                              \
          _Pragma("unroll")                                                         \
          for (int q = 0; q < 8; ++q)                                               \
            br[cur][m][kh][q] = (m ? bsrc1 : bsrc0)[                                \
                (size_t)(((ks) + 2) * BKD + kh * 16 + hi8 + q) * MLPD];             \
    }                                                                               \
    __builtin_amdgcn_sched_barrier(0);                                              \
    _Pragma("unroll")                                                               \
    for (int g = 0; g < 2; ++g)                                                     \
      _Pragma("unroll")                                                             \
      for (int kh = 0; kh < 2; ++kh) {                                              \
        int idx = ((wr * 2 + g) * 4 + kh * 2 + hi) * 256 + lo * 4;                  \
        f32x4 q0 = *(const f32x4*)&Ash[cur][idx];                                   \
        f32x4 q1 = *(const f32x4*)&Ash[cur][idx + 128];                             \
        bf16x8 av;                                                                  \
        _Pragma("unroll")                                                           \
        for (int q = 0; q < 4; ++q) { av[q] = (__bf16)q0[q]; av[4 + q] = (__bf16)q1[q]; } \
        acc0[g] = __builtin_amdgcn_mfma_f32_32x32x16_bf16(av, bv0[kh], acc0[g], 0, 0, 0); \
        acc1[g] = __builtin_amdgcn_mfma_f32_32x32x16_bf16(av, bv1[kh], acc1[g], 0, 0, 0); \
      }                                                                             \
  }

  for (int ks = 0; ks < NT; ks += 2) {
    G1_PHASE(0, ks);
    G1_PHASE(1, ks + 1);
  }
#undef G1_PHASE

  // epilogue: silu(h0)*h1 -> bf16 inter. 32x32 C map: col=lo, row=(r&3)+8*(r>>2)+4*hi
  #pragma unroll
  for (int g = 0; g < 2; ++g)
    #pragma unroll
    for (int r = 0; r < 16; ++r) {
      int rl = mc * 128 + wr * 64 + g * 32 + (r & 3) + 8 * (r >> 2) + 4 * hi;
      if (rl < Me) {
        float h0 = acc0[g][r], h1 = acc1[g][r];
        float s = h0 / (1.f + expf(-h0)) * h1;
        inter[(size_t)(rs + rl) * MLPD + nb + wc * 32 + lo] = (__hip_bfloat16)s;
      }
    }
}

// ---------------- grouped GEMM 2: out_sorted = inter @ wo ----------------
// Same structure: A (bf16 inter) gl_lds dbuf fragment-major; B (wo) reg-direct
// depth-2; counted vmcnt(16).
template <typename OS_T>
__global__ __launch_bounds__(256, 3) void gemm2_k(
    const __hip_bfloat16* __restrict__ inter, const float* __restrict__ wo,
    const int* __restrict__ counts, const int* __restrict__ base,
    OS_T* __restrict__ os) {
  int e = blockIdx.z;
  int Me = counts[e];
  int mc = blockIdx.y;
  if (mc * 128 >= Me) return;
  int rs = base[e];
  int nb = blockIdx.x * 64;
  int t = threadIdx.x;
  int wv = t >> 6, l = t & 63;
  int wr = wv >> 1, wc = wv & 1;
  int lo = l & 31, hi = l >> 5;
  int hi8 = hi * 8;

  __shared__ __bf16 A2[2][4096];   // 2 x 8KB [slot8][lane64][8bf16]

  int rga = mc * 128 + wv * 32 + lo; rga = rga < Me ? rga : Me - 1;
  const __hip_bfloat16* ab = inter + (size_t)(rs + rga) * MLPD + hi8;
  const float* bsrc = wo + (size_t)e * MLPD * EMBD + nb + wc * 32 + lo;

  float br[2][2][8];   // [set][kh][q]
  f32x16 acc[2];
  #pragma unroll
  for (int g = 0; g < 2; ++g)
    #pragma unroll
    for (int r = 0; r < 16; ++r) acc[g][r] = 0.f;

  const int NT = MLPD / BKD;  // 64 (even)

  #pragma unroll
  for (int kh = 0; kh < 2; ++kh)
    gl16(ab + kh * 16, &A2[0][(wv * 2 + kh) * 512]);
  #pragma unroll
  for (int kh = 0; kh < 2; ++kh)
    #pragma unroll
    for (int q = 0; q < 8; ++q) {
      br[0][kh][q] = bsrc[(size_t)(kh * 16 + hi8 + q) * EMBD];
      br[1][kh][q] = bsrc[(size_t)(BKD + kh * 16 + hi8 + q) * EMBD];
    }

#define G2_PHASE(cur, ks)                                                           \
  {                                                                                 \
    if ((ks) + 1 < NT) asm volatile("s_waitcnt vmcnt(16)" ::: "memory");            \
    else               asm volatile("s_waitcnt vmcnt(0)" ::: "memory");             \
    __builtin_amdgcn_s_barrier();                                                   \
    bf16x8 bv[2];                                                                   \
    _Pragma("unroll")                                                               \
    for (int kh = 0; kh < 2; ++kh)                                                  \
      _Pragma("unroll")                                                             \
      for (int q = 0; q < 8; ++q) bv[kh][q] = (__bf16)br[cur][kh][q];               \
    __builtin_amdgcn_sched_barrier(0);                                              \
    if ((ks) + 1 < NT) {                                                            \
      _Pragma("unroll")                                                             \
      for (int kh = 0; kh < 2; ++kh)                                                \
        gl16(ab + ((ks) + 1) * BKD + kh * 16, &A2[(cur) ^ 1][(wv * 2 + kh) * 512]); \
    }                                                                               \
    __builtin_amdgcn_sched_barrier(0);                                              \
    if ((ks) + 2 < NT) {                                                            \
      _Pragma("unroll")                                                             \
      for (int kh = 0; kh < 2; ++kh)                                                \
        _Pragma("unroll")                                                           \
        for (int q = 0; q < 8; ++q)                                                 \
          br[cur][kh][q] = bsrc[(size_t)(((ks) + 2) * BKD + kh * 16 + hi8 + q) * EMBD]; \
    }                                                                               \
    __builtin_amdgcn_sched_barrier(0);                                              \
    _Pragma("unroll")                                                               \
    for (int g = 0; g < 2; ++g)                                                     \
      _Pragma("unroll")                                                             \
      for (int kh = 0; kh < 2; ++kh) {                                              \
        bf16x8 av = *(const bf16x8*)&A2[cur][((wr * 2 + g) * 2 + kh) * 512 + l * 8];\
        acc[g] = __builtin_amdgcn_mfma_f32_32x32x16_bf16(av, bv[kh], acc[g], 0, 0, 0); \
      }                                                                             \
  }

  for (int ks = 0; ks < NT; ks += 2) {
    G2_PHASE(0, ks);
    G2_PHASE(1, ks + 1);
  }
#undef G2_PHASE

  #pragma unroll
  for (int g = 0; g < 2; ++g)
    #pragma unroll
    for (int r = 0; r < 16; ++r) {
      int rl = mc * 128 + wr * 64 + g * 32 + (r & 3) + 8 * (r >> 2) + 4 * hi;
      if (rl < Me)
        os[(size_t)(rs + rl) * EMBD + nb + wc * 32 + lo] = (OS_T)acc[g][r];
    }
}

// ---------------- combine: out[t] = w1*os[r1] + w2*os[r2] ----------------
template <typename OS_T>
__global__ __launch_bounds__(256) void combine_k(
    const OS_T* __restrict__ os, const int* __restrict__ f2r,
    const float* __restrict__ wf, float* __restrict__ out) {
  int t = blockIdx.x;
  int c = threadIdx.x * 4;
  int r0 = f2r[2 * t], r1 = f2r[2 * t + 1];
  float wa = wf[2 * t], wb = wf[2 * t + 1];
  const OS_T* pa = os + (size_t)r0 * EMBD + c;
  const OS_T* pb = os + (size_t)r1 * EMBD + c;
  float4 o;
  o.x = wa * (float)pa[0] + wb * (float)pb[0];
  o.y = wa * (float)pa[1] + wb * (float)pb[1];
  o.z = wa * (float)pa[2] + wb * (float)pb[2];
  o.w = wa * (float)pa[3] + wb * (float)pb[3];
  *(float4*)(out + (size_t)t * EMBD + c) = o;
}

// ---------------- launcher ----------------
extern "C" void kernel_launch(void* const* d_in, const int* in_sizes, int n_in,
                              void* d_out, int out_size, void* d_ws, size_t ws_size,
                              hipStream_t stream) {
  const float* x  = (const float*)d_in[0];
  const float* gk = (const float*)d_in[1];
  const float* w0 = (const float*)d_in[2];
  const float* w1 = (const float*)d_in[3];
  const float* wo = (const float*)d_in[4];
  float* out = (float*)d_out;
  char* ws = (char*)d_ws;

  int*   counts = (int*)(ws + OFF_COUNTS);
  int*   basep  = (int*)(ws + OFF_BASE);
  int*   run    = (int*)(ws + OFF_RUN);
  int*   ef     = (int*)(ws + OFF_EFLAT);
  float* wfl    = (float*)(ws + OFF_WFLAT);
  int*   rowtok = (int*)(ws + OFF_ROWTOK);
  int*   f2r    = (int*)(ws + OFF_F2R);
  __hip_bfloat16* inter = (__hip_bfloat16*)(ws + OFF_INTER);

  hipMemsetAsync(ws, 0, 1024, stream);
  router_topk<<<NTOK / 4, 256, 0, stream>>>(x, gk, ef, wfl);
  hist_k<<<NFLAT / 256, 256, 0, stream>>>(ef, counts);
  scan_k<<<1, 64, 0, stream>>>(counts, basep);
  scatter_k<<<NFLAT / 256, 256, 0, stream>>>(ef, basep, run, rowtok, f2r);
  gemm1_k<<<dim3(MLPD / 64, MAXCH, NEXP), 256, 0, stream>>>(x, w0, w1, counts, basep, rowtok, inter);

  if (ws_size >= NEED_F32) {
    float* os = (float*)(ws + OFF_OS);
    gemm2_k<float><<<dim3(EMBD / 64, MAXCH, NEXP), 256, 0, stream>>>(inter, wo, counts, basep, os);
    combine_k<float><<<NTOK, 256, 0, stream>>>(os, f2r, wfl, out);
  } else {
    __hip_bfloat16* os = (__hip_bfloat16*)(ws + OFF_OS);
    gemm2_k<__hip_bfloat16><<<dim3(EMBD / 64, MAXCH, NEXP), 256, 0, stream>>>(inter, wo, counts, basep, os);
    combine_k<__hip_bfloat16><<<NTOK, 256, 0, stream>>>(os, f2r, wfl, out);
  }
}

// Round 10
// 938.004 us; speedup vs baseline: 1.2151x; 1.2151x over previous
//
#include <hip/hip_runtime.h>
#include <hip/hip_bf16.h>
#include <math.h>

#define NTOK   8192      // B*S tokens
#define NEXP   64
#define EMBD   1024
#define MLPD   2048
#define TOPK   2
#define NFLAT  (NTOK * TOPK)
#define BKD    32        // K tile
#define MAXCH  8         // max m-chunks of 128 (mean Me=256)

typedef __attribute__((ext_vector_type(4)))  float  f32x4;
typedef __attribute__((ext_vector_type(16))) float  f32x16;
typedef __attribute__((ext_vector_type(8)))  __bf16 bf16x8;

// global -> LDS direct (16B/lane). LDS dest = wave-uniform base + lane*16.
__device__ __forceinline__ void gl16(const void* g, void* lds_base) {
  __builtin_amdgcn_global_load_lds(
      (const __attribute__((address_space(1))) unsigned int*)g,
      (__attribute__((address_space(3))) unsigned int*)lds_base, 16, 0, 0);
}

// ---------------- workspace layout (bytes) ----------------
#define OFF_COUNTS 0
#define OFF_BASE   256
#define OFF_RUN    512
#define OFF_EFLAT  1024
#define OFF_WFLAT  (1024 + 65536)
#define OFF_ROWTOK (1024 + 2 * 65536)
#define OFF_F2R    (1024 + 3 * 65536)
#define OFF_INTER  (1024 + 4 * 65536)                       // bf16 [16384][2048]
#define OFF_OS     (OFF_INTER + (size_t)NFLAT * MLPD * 2)   // out_sorted
#define OFF_XB     OFF_OS   // xb (16MB bf16 x) aliases os: xb dead before gemm2 writes os
#define NEED_F32   (OFF_OS + (size_t)NFLAT * EMBD * 4)

// ---------------- x -> bf16 convert ----------------
__global__ __launch_bounds__(256) void cvt_x_k(const float* __restrict__ x,
                                               __bf16* __restrict__ xb) {
  size_t i = ((size_t)blockIdx.x * 256 + threadIdx.x) * 8;
  f32x4 f0 = *(const f32x4*)(x + i);
  f32x4 f1 = *(const f32x4*)(x + i + 4);
  bf16x8 v;
  #pragma unroll
  for (int q = 0; q < 4; ++q) { v[q] = (__bf16)f0[q]; v[4 + q] = (__bf16)f1[q]; }
  *(bf16x8*)(xb + i) = v;
}

// ---------------- router: logits + top-2 + softmax ----------------
__global__ __launch_bounds__(256) void router_topk(
    const float* __restrict__ x, const float* __restrict__ gk,
    int* __restrict__ e_flat, float* __restrict__ w_flat) {
  int t = blockIdx.x * 4 + (threadIdx.x >> 6);
  int l = threadIdx.x & 63;
  const float* xr = x + (size_t)t * EMBD;
  float acc = 0.f;
  #pragma unroll 8
  for (int i = 0; i < EMBD; ++i)
    acc = fmaf(xr[i], gk[i * NEXP + l], acc);
  float m = acc;
  for (int o = 32; o; o >>= 1) m = fmaxf(m, __shfl_xor(m, o));
  unsigned long long b1 = __ballot(acc == m);
  int i1 = __ffsll(b1) - 1;
  float v2 = (l == i1) ? -INFINITY : acc;
  float m2 = v2;
  for (int o = 32; o; o >>= 1) m2 = fmaxf(m2, __shfl_xor(m2, o));
  unsigned long long b2 = __ballot(v2 == m2);
  int i2 = __ffsll(b2) - 1;
  if (l == 0) {
    float e2 = expf(m2 - m);
    float inv = 1.f / (1.f + e2);
    e_flat[2 * t] = i1;  e_flat[2 * t + 1] = i2;
    w_flat[2 * t] = inv; w_flat[2 * t + 1] = e2 * inv;
  }
}

// ---------------- histogram / scan / scatter ----------------
__global__ void hist_k(const int* __restrict__ ef, int* __restrict__ counts) {
  int j = blockIdx.x * 256 + threadIdx.x;
  if (j < NFLAT) atomicAdd(&counts[ef[j]], 1);
}

__global__ void scan_k(const int* __restrict__ counts, int* __restrict__ base) {
  if (threadIdx.x == 0) {
    int s = 0;
    for (int e = 0; e < NEXP; ++e) { base[e] = s; s += counts[e]; }
  }
}

__global__ void scatter_k(const int* __restrict__ ef, const int* __restrict__ base,
                          int* __restrict__ run, int* __restrict__ rowtok,
                          int* __restrict__ f2r) {
  int j = blockIdx.x * 256 + threadIdx.x;
  if (j < NFLAT) {
    int e = ef[j];
    int r = base[e] + atomicAdd(&run[e], 1);
    f2r[j] = r;
    rowtok[r] = j >> 1;
  }
}

// ---------------- grouped GEMM 1: inter = silu(x@w0) * (x@w1) ----------------
// 128m x 64n x 32k; 4 waves 2x2 (wave 64m x 32n); MFMA 32x32x16.
// TRIPLE-buffered LDS ring; every wave stages an identical 6-gl16 share of
// stage(ks+2) per step; top-of-step counted vmcnt(6) -> each stage flies ~2
// full steps. ONE barrier per step. A = bf16 fragment-major; B = f32 [k][n].
__global__ __launch_bounds__(256, 2) void gemm1_k(
    const __bf16* __restrict__ xb, const float* __restrict__ w0,
    const float* __restrict__ w1, const int* __restrict__ counts,
    const int* __restrict__ base, const int* __restrict__ rowtok,
    __hip_bfloat16* __restrict__ inter) {
  int e = blockIdx.z;
  int Me = counts[e];
  int mc = blockIdx.y;
  if (mc * 128 >= Me) return;
  int rs = base[e];
  int nb = blockIdx.x * 64;
  int t = threadIdx.x;
  int wv = t >> 6, l = t & 63;
  int wr = wv >> 1, wc = wv & 1;
  int lo = l & 31, hi = l >> 5;

  __shared__ __bf16 A1[3][4096];   // 3 x 8KB  [slot=g*2+kh][lane][8bf16]
  __shared__ float  B1[3][4096];   // 3 x 16KB [mat][k32][n64]

  // A: wave wv stages m-group g=wv (rows mc*128+wv*32+lo), slots wv*2+kh
  int rga = mc * 128 + wv * 32 + lo; rga = rga < Me ? rga : Me - 1;
  const __bf16* abase = xb + (size_t)rowtok[rs + rga] * EMBD + hi * 8;
  // B: wave wv stages mat wv>>1, k-rows [(wv&1)*16, +16)
  int bm = wv >> 1, bk0 = (wv & 1) * 16;
  const float* wsel = bm ? w1 : w0;
  const float* wbase = wsel + (size_t)e * EMBD * MLPD + nb + (l & 15) * 4 +
                       (size_t)(l >> 4) * MLPD;

  auto STAGE = [&](int ks, int buf) {
    int kk = ks * BKD;
    #pragma unroll
    for (int kh = 0; kh < 2; ++kh)
      gl16(abase + kk + kh * 16, &A1[buf][(wv * 2 + kh) * 512]);
    #pragma unroll
    for (int j = 0; j < 4; ++j)
      gl16(wbase + (size_t)(kk + bk0 + j * 4) * MLPD,
           &B1[buf][bm * 2048 + (bk0 + j * 4) * 64]);
  };

  f32x16 acc0[2], acc1[2];
  #pragma unroll
  for (int g = 0; g < 2; ++g)
    #pragma unroll
    for (int r = 0; r < 16; ++r) { acc0[g][r] = 0.f; acc1[g][r] = 0.f; }

  const int NT = EMBD / BKD;  // 32
  STAGE(0, 0);
  STAGE(1, 1);
  int bufR = 0, bufW = 2;
  for (int ks = 0; ks < NT; ++ks) {
    if (ks + 1 < NT) asm volatile("s_waitcnt vmcnt(6)" ::: "memory");
    else             asm volatile("s_waitcnt vmcnt(0)" ::: "memory");
    __builtin_amdgcn_sched_barrier(0);
    __builtin_amdgcn_s_barrier();
    if (ks + 2 < NT) STAGE(ks + 2, bufW);

    bf16x8 av[2][2];
    #pragma unroll
    for (int g = 0; g < 2; ++g)
      #pragma unroll
      for (int kh = 0; kh < 2; ++kh)
        av[g][kh] = *(const bf16x8*)&A1[bufR][((wr * 2 + g) * 2 + kh) * 512 + l * 8];
    float b[2][2][8];
    #pragma unroll
    for (int m = 0; m < 2; ++m)
      #pragma unroll
      for (int kh = 0; kh < 2; ++kh) {
        int bi = m * 2048 + (kh * 16 + hi * 8) * 64 + wc * 32 + lo;
        #pragma unroll
        for (int q = 0; q < 8; ++q) b[m][kh][q] = B1[bufR][bi + q * 64];
      }
    bf16x8 bv0[2], bv1[2];
    #pragma unroll
    for (int kh = 0; kh < 2; ++kh)
      #pragma unroll
      for (int q = 0; q < 8; ++q) {
        bv0[kh][q] = (__bf16)b[0][kh][q];
        bv1[kh][q] = (__bf16)b[1][kh][q];
      }
    #pragma unroll
    for (int kh = 0; kh < 2; ++kh)
      #pragma unroll
      for (int g = 0; g < 2; ++g) {
        acc0[g] = __builtin_amdgcn_mfma_f32_32x32x16_bf16(av[g][kh], bv0[kh], acc0[g], 0, 0, 0);
        acc1[g] = __builtin_amdgcn_mfma_f32_32x32x16_bf16(av[g][kh], bv1[kh], acc1[g], 0, 0, 0);
      }
    bufR = bufR == 2 ? 0 : bufR + 1;
    bufW = bufW == 2 ? 0 : bufW + 1;
  }

  // epilogue: silu(h0)*h1 -> bf16 inter. 32x32 C map: col=lo, row=(r&3)+8*(r>>2)+4*hi
  #pragma unroll
  for (int g = 0; g < 2; ++g)
    #pragma unroll
    for (int r = 0; r < 16; ++r) {
      int rl = mc * 128 + wr * 64 + g * 32 + (r & 3) + 8 * (r >> 2) + 4 * hi;
      if (rl < Me) {
        float h0 = acc0[g][r], h1 = acc1[g][r];
        float s = h0 / (1.f + expf(-h0)) * h1;
        inter[(size_t)(rs + rl) * MLPD + nb + wc * 32 + lo] = (__hip_bfloat16)s;
      }
    }
}

// ---------------- grouped GEMM 2: out_sorted = inter @ wo ----------------
// Same triple-buffer counted-vmcnt structure; 4 gl16/wave/step, vmcnt(4).
template <typename OS_T>
__global__ __launch_bounds__(256, 3) void gemm2_k(
    const __hip_bfloat16* __restrict__ inter, const float* __restrict__ wo,
    const int* __restrict__ counts, const int* __restrict__ base,
    OS_T* __restrict__ os) {
  int e = blockIdx.z;
  int Me = counts[e];
  int mc = blockIdx.y;
  if (mc * 128 >= Me) return;
  int rs = base[e];
  int nb = blockIdx.x * 64;
  int t = threadIdx.x;
  int wv = t >> 6, l = t & 63;
  int wr = wv >> 1, wc = wv & 1;
  int lo = l & 31, hi = l >> 5;

  __shared__ __bf16 A2[3][4096];   // 3 x 8KB [slot=g*2+kh][lane][8bf16]
  __shared__ float  B2[3][2048];   // 3 x 8KB [k32][n64]

  int rga = mc * 128 + wv * 32 + lo; rga = rga < Me ? rga : Me - 1;
  const __bf16* abase = (const __bf16*)inter + (size_t)(rs + rga) * MLPD + hi * 8;
  const float* wbase = wo + (size_t)e * MLPD * EMBD + nb + (l & 15) * 4 +
                       (size_t)(l >> 4) * EMBD;

  auto STAGE = [&](int ks, int buf) {
    int kk = ks * BKD;
    #pragma unroll
    for (int kh = 0; kh < 2; ++kh)
      gl16(abase + kk + kh * 16, &A2[buf][(wv * 2 + kh) * 512]);
    #pragma unroll
    for (int j = 0; j < 2; ++j)
      gl16(wbase + (size_t)(kk + wv * 8 + j * 4) * EMBD,
           &B2[buf][(wv * 8 + j * 4) * 64]);
  };

  f32x16 acc[2];
  #pragma unroll
  for (int g = 0; g < 2; ++g)
    #pragma unroll
    for (int r = 0; r < 16; ++r) acc[g][r] = 0.f;

  const int NT = MLPD / BKD;  // 64
  STAGE(0, 0);
  STAGE(1, 1);
  int bufR = 0, bufW = 2;
  for (int ks = 0; ks < NT; ++ks) {
    if (ks + 1 < NT) asm volatile("s_waitcnt vmcnt(4)" ::: "memory");
    else             asm volatile("s_waitcnt vmcnt(0)" ::: "memory");
    __builtin_amdgcn_sched_barrier(0);
    __builtin_amdgcn_s_barrier();
    if (ks + 2 < NT) STAGE(ks + 2, bufW);

    bf16x8 av[2][2];
    #pragma unroll
    for (int g = 0; g < 2; ++g)
      #pragma unroll
      for (int kh = 0; kh < 2; ++kh)
        av[g][kh] = *(const bf16x8*)&A2[bufR][((wr * 2 + g) * 2 + kh) * 512 + l * 8];
    float b[2][8];
    #pragma unroll
    for (int kh = 0; kh < 2; ++kh) {
      int bi = (kh * 16 + hi * 8) * 64 + wc * 32 + lo;
      #pragma unroll
      for (int q = 0; q < 8; ++q) b[kh][q] = B2[bufR][bi + q * 64];
    }
    bf16x8 bv[2];
    #pragma unroll
    for (int kh = 0; kh < 2; ++kh)
      #pragma unroll
      for (int q = 0; q < 8; ++q) bv[kh][q] = (__bf16)b[kh][q];
    #pragma unroll
    for (int kh = 0; kh < 2; ++kh)
      #pragma unroll
      for (int g = 0; g < 2; ++g)
        acc[g] = __builtin_amdgcn_mfma_f32_32x32x16_bf16(av[g][kh], bv[kh], acc[g], 0, 0, 0);
    bufR = bufR == 2 ? 0 : bufR + 1;
    bufW = bufW == 2 ? 0 : bufW + 1;
  }

  #pragma unroll
  for (int g = 0; g < 2; ++g)
    #pragma unroll
    for (int r = 0; r < 16; ++r) {
      int rl = mc * 128 + wr * 64 + g * 32 + (r & 3) + 8 * (r >> 2) + 4 * hi;
      if (rl < Me)
        os[(size_t)(rs + rl) * EMBD + nb + wc * 32 + lo] = (OS_T)acc[g][r];
    }
}

// ---------------- combine: out[t] = w1*os[r1] + w2*os[r2] ----------------
template <typename OS_T>
__global__ __launch_bounds__(256) void combine_k(
    const OS_T* __restrict__ os, const int* __restrict__ f2r,
    const float* __restrict__ wf, float* __restrict__ out) {
  int t = blockIdx.x;
  int c = threadIdx.x * 4;
  int r0 = f2r[2 * t], r1 = f2r[2 * t + 1];
  float wa = wf[2 * t], wb = wf[2 * t + 1];
  const OS_T* pa = os + (size_t)r0 * EMBD + c;
  const OS_T* pb = os + (size_t)r1 * EMBD + c;
  float4 o;
  o.x = wa * (float)pa[0] + wb * (float)pb[0];
  o.y = wa * (float)pa[1] + wb * (float)pb[1];
  o.z = wa * (float)pa[2] + wb * (float)pb[2];
  o.w = wa * (float)pa[3] + wb * (float)pb[3];
  *(float4*)(out + (size_t)t * EMBD + c) = o;
}

// ---------------- launcher ----------------
extern "C" void kernel_launch(void* const* d_in, const int* in_sizes, int n_in,
                              void* d_out, int out_size, void* d_ws, size_t ws_size,
                              hipStream_t stream) {
  const float* x  = (const float*)d_in[0];
  const float* gk = (const float*)d_in[1];
  const float* w0 = (const float*)d_in[2];
  const float* w1 = (const float*)d_in[3];
  const float* wo = (const float*)d_in[4];
  float* out = (float*)d_out;
  char* ws = (char*)d_ws;

  int*   counts = (int*)(ws + OFF_COUNTS);
  int*   basep  = (int*)(ws + OFF_BASE);
  int*   run    = (int*)(ws + OFF_RUN);
  int*   ef     = (int*)(ws + OFF_EFLAT);
  float* wfl    = (float*)(ws + OFF_WFLAT);
  int*   rowtok = (int*)(ws + OFF_ROWTOK);
  int*   f2r    = (int*)(ws + OFF_F2R);
  __hip_bfloat16* inter = (__hip_bfloat16*)(ws + OFF_INTER);
  __bf16* xb = (__bf16*)(ws + OFF_XB);   // aliases os region (dead until gemm2)

  hipMemsetAsync(ws, 0, 1024, stream);
  cvt_x_k<<<NTOK * EMBD / (256 * 8), 256, 0, stream>>>(x, xb);
  router_topk<<<NTOK / 4, 256, 0, stream>>>(x, gk, ef, wfl);
  hist_k<<<NFLAT / 256, 256, 0, stream>>>(ef, counts);
  scan_k<<<1, 64, 0, stream>>>(counts, basep);
  scatter_k<<<NFLAT / 256, 256, 0, stream>>>(ef, basep, run, rowtok, f2r);
  gemm1_k<<<dim3(MLPD / 64, MAXCH, NEXP), 256, 0, stream>>>(xb, w0, w1, counts, basep, rowtok, inter);

  if (ws_size >= NEED_F32) {
    float* os = (float*)(ws + OFF_OS);
    gemm2_k<float><<<dim3(EMBD / 64, MAXCH, NEXP), 256, 0, stream>>>(inter, wo, counts, basep, os);
    combine_k<float><<<NTOK, 256, 0, stream>>>(os, f2r, wfl, out);
  } else {
    __hip_bfloat16* os = (__hip_bfloat16*)(ws + OFF_OS);
    gemm2_k<__hip_bfloat16><<<dim3(EMBD / 64, MAXCH, NEXP), 256, 0, stream>>>(inter, wo, counts, basep, os);
    combine_k<__hip_bfloat16><<<NTOK, 256, 0, stream>>>(os, f2r, wfl, out);
  }
}